// Round 1
// 397.110 us; speedup vs baseline: 1.2127x; 1.2127x over previous
//
#include <hip/hip_runtime.h>

#define IN_CH 16
#define HID 128
#define HEADS 4
#define NEG 0.2f
#define LN_EPS 1e-5f

typedef short bf16x8 __attribute__((ext_vector_type(8)));
typedef float f32x4 __attribute__((ext_vector_type(4)));

__device__ __forceinline__ float bf2f(unsigned short u) {
  return __uint_as_float(((unsigned)u) << 16);
}
__device__ __forceinline__ float bflo(unsigned u) {
  return __uint_as_float(u << 16);
}
__device__ __forceinline__ float bfhi(unsigned u) {
  return __uint_as_float(u & 0xffff0000u);
}
__device__ __forceinline__ unsigned short f2bf(float f) {
  unsigned u = __float_as_uint(f);
  unsigned r = (u + 0x7fffu + ((u >> 16) & 1u)) >> 16;  // RNE
  return (unsigned short)r;
}

// ---------------------------------------------------------------------------
// h1 = x @ W1 (N x 16 @ 16 x 128) -> bf16, fused per-head attention logits.
// ---------------------------------------------------------------------------
__global__ __launch_bounds__(128) void k_gemm1(
    const float* __restrict__ x, const float* __restrict__ W1,
    const float* __restrict__ a_src, const float* __restrict__ a_dst,
    unsigned short* __restrict__ hb, float* __restrict__ asrc,
    float* __restrict__ adst, int N) {
  int n = blockIdx.x;
  int c = threadIdx.x;
  __shared__ float xs[IN_CH];
  if (c < IN_CH) xs[c] = x[n * IN_CH + c];
  __syncthreads();
  float acc = 0.f;
#pragma unroll
  for (int k = 0; k < IN_CH; ++k) acc += xs[k] * W1[k * HID + c];
  hb[(size_t)n * HID + c] = f2bf(acc);
  float av = acc * a_src[c];
  float dv = acc * a_dst[c];
#pragma unroll
  for (int o = 16; o > 0; o >>= 1) {
    av += __shfl_down(av, o, 32);
    dv += __shfl_down(dv, o, 32);
  }
  if ((c & 31) == 0) {
    asrc[n * HEADS + (c >> 5)] = av;
    adst[n * HEADS + (c >> 5)] = dv;
  }
}

// ---------------------------------------------------------------------------
// CSR build: degree count + per-edge rank (rank = old count, free from the
// same atomicAdd). Enables a one-pass atomic-free scatter.
// ---------------------------------------------------------------------------
__global__ __launch_bounds__(256) void k_deg(
    const int* __restrict__ ei, int E, int Etot, int* __restrict__ deg,
    int* __restrict__ rank) {
  int e = blockIdx.x * 256 + threadIdx.x;
  if (e >= Etot) return;
  int d = (e < E) ? ei[E + e] : (e - E);
  rank[e] = atomicAdd(&deg[d], 1);
}

__global__ __launch_bounds__(256) void k_scan1(
    const int* __restrict__ deg, int* __restrict__ part, int* __restrict__ aux,
    int N) {
  int i = blockIdx.x * 256 + threadIdx.x;
  int v = (i < N) ? deg[i] : 0;
  int lane = threadIdx.x & 63, w = threadIdx.x >> 6;
  int inc = v;
#pragma unroll
  for (int o = 1; o < 64; o <<= 1) {
    int t = __shfl_up(inc, o, 64);
    if (lane >= o) inc += t;
  }
  __shared__ int wsum[4];
  if (lane == 63) wsum[w] = inc;
  __syncthreads();
  int woff = 0;
#pragma unroll
  for (int k = 0; k < 4; ++k)
    if (k < w) woff += wsum[k];
  if (i < N) part[i] = woff + inc - v;
  if (threadIdx.x == 255) aux[blockIdx.x] = woff + inc;
}

__global__ __launch_bounds__(512) void k_scan2(int* __restrict__ aux, int nb) {
  int i = threadIdx.x;
  int v = (i < nb) ? aux[i] : 0;
  int lane = i & 63, w = i >> 6;
  int inc = v;
#pragma unroll
  for (int o = 1; o < 64; o <<= 1) {
    int t = __shfl_up(inc, o, 64);
    if (lane >= o) inc += t;
  }
  __shared__ int wsum[8];
  if (lane == 63) wsum[w] = inc;
  __syncthreads();
  int woff = 0;
#pragma unroll
  for (int k = 0; k < 8; ++k)
    if (k < w) woff += wsum[k];
  if (i < nb) aux[i] = woff + inc - v;
}

__global__ __launch_bounds__(256) void k_scan3(
    const int* __restrict__ part, const int* __restrict__ aux,
    int* __restrict__ rowstart, int N, int Etot) {
  int i = blockIdx.x * 256 + threadIdx.x;
  if (i < N) rowstart[i] = part[i] + aux[blockIdx.x];
  if (i == 0) rowstart[N] = Etot;
}

// ---------------------------------------------------------------------------
// One-pass scatter: pos = rowstart[dst] + rank (no atomics, single ei read).
// ---------------------------------------------------------------------------
__global__ __launch_bounds__(256) void k_scatter(
    const int* __restrict__ ei, const int* __restrict__ rowstart,
    const int* __restrict__ rank, int E, int Etot, int* __restrict__ csr_src) {
  int e = blockIdx.x * 256 + threadIdx.x;
  if (e >= Etot) return;
  int d = (e < E) ? ei[E + e] : (e - E);
  int s = (e < E) ? ei[e] : d;
  csr_src[rowstart[d] + rank[e]] = s;
}

// ---------------------------------------------------------------------------
// Fused GAT agg + bias + ELU + LN, layer 1 (4 heads).
// 16 threads/node, 8 channels/lane, uint4 (16B) payload gathers.
// ---------------------------------------------------------------------------
__global__ __launch_bounds__(256) void k_agg1(
    const int* __restrict__ rowstart, const int* __restrict__ csr_src,
    const float* __restrict__ asrc, const float* __restrict__ adst,
    const unsigned short* __restrict__ hb, const float* __restrict__ bias,
    const float* __restrict__ g, const float* __restrict__ beta,
    unsigned short* __restrict__ outb, int N) {
  int d = blockIdx.x * 16 + (threadIdx.x >> 4);
  if (d >= N) return;
  int lane = threadIdx.x & 15;
  int c0 = lane << 3;  // 8 channels per lane
  int hd = lane >> 2;  // head = c0/32
  float ad = adst[d * HEADS + hd];
  int beg = rowstart[d], end = rowstart[d + 1];
  float a0 = 0.f, a1 = 0.f, a2 = 0.f, a3 = 0.f;
  float a4 = 0.f, a5 = 0.f, a6 = 0.f, a7 = 0.f, wsum = 0.f;
  int i = beg;
  for (; i + 4 <= end; i += 4) {
    int sA = csr_src[i], sB = csr_src[i + 1];
    int sC = csr_src[i + 2], sD = csr_src[i + 3];
    float vA = asrc[sA * HEADS + hd] + ad;
    float vB = asrc[sB * HEADS + hd] + ad;
    float vC = asrc[sC * HEADS + hd] + ad;
    float vD = asrc[sD * HEADS + hd] + ad;
    uint4 pA = *(const uint4*)(hb + (size_t)sA * HID + c0);
    uint4 pB = *(const uint4*)(hb + (size_t)sB * HID + c0);
    uint4 pC = *(const uint4*)(hb + (size_t)sC * HID + c0);
    uint4 pD = *(const uint4*)(hb + (size_t)sD * HID + c0);
    vA = vA < 0.f ? NEG * vA : vA;
    vB = vB < 0.f ? NEG * vB : vB;
    vC = vC < 0.f ? NEG * vC : vC;
    vD = vD < 0.f ? NEG * vD : vD;
    float wA = __expf(vA), wB = __expf(vB);
    float wC = __expf(vC), wD = __expf(vD);
    wsum += (wA + wB) + (wC + wD);
    a0 += wA * bflo(pA.x) + wB * bflo(pB.x) + wC * bflo(pC.x) + wD * bflo(pD.x);
    a1 += wA * bfhi(pA.x) + wB * bfhi(pB.x) + wC * bfhi(pC.x) + wD * bfhi(pD.x);
    a2 += wA * bflo(pA.y) + wB * bflo(pB.y) + wC * bflo(pC.y) + wD * bflo(pD.y);
    a3 += wA * bfhi(pA.y) + wB * bfhi(pB.y) + wC * bfhi(pC.y) + wD * bfhi(pD.y);
    a4 += wA * bflo(pA.z) + wB * bflo(pB.z) + wC * bflo(pC.z) + wD * bflo(pD.z);
    a5 += wA * bfhi(pA.z) + wB * bfhi(pB.z) + wC * bfhi(pC.z) + wD * bfhi(pD.z);
    a6 += wA * bflo(pA.w) + wB * bflo(pB.w) + wC * bflo(pC.w) + wD * bflo(pD.w);
    a7 += wA * bfhi(pA.w) + wB * bfhi(pB.w) + wC * bfhi(pC.w) + wD * bfhi(pD.w);
  }
  for (; i < end; ++i) {
    int sA = csr_src[i];
    float vA = asrc[sA * HEADS + hd] + ad;
    uint4 pA = *(const uint4*)(hb + (size_t)sA * HID + c0);
    vA = vA < 0.f ? NEG * vA : vA;
    float wA = __expf(vA);
    wsum += wA;
    a0 += wA * bflo(pA.x);
    a1 += wA * bfhi(pA.x);
    a2 += wA * bflo(pA.y);
    a3 += wA * bfhi(pA.y);
    a4 += wA * bflo(pA.z);
    a5 += wA * bfhi(pA.z);
    a6 += wA * bflo(pA.w);
    a7 += wA * bfhi(pA.w);
  }
  float rw = 1.f / wsum;
  float v0 = a0 * rw + bias[c0 + 0];
  float v1 = a1 * rw + bias[c0 + 1];
  float v2 = a2 * rw + bias[c0 + 2];
  float v3 = a3 * rw + bias[c0 + 3];
  float v4 = a4 * rw + bias[c0 + 4];
  float v5 = a5 * rw + bias[c0 + 5];
  float v6 = a6 * rw + bias[c0 + 6];
  float v7 = a7 * rw + bias[c0 + 7];
  v0 = v0 > 0.f ? v0 : (__expf(v0) - 1.f);
  v1 = v1 > 0.f ? v1 : (__expf(v1) - 1.f);
  v2 = v2 > 0.f ? v2 : (__expf(v2) - 1.f);
  v3 = v3 > 0.f ? v3 : (__expf(v3) - 1.f);
  v4 = v4 > 0.f ? v4 : (__expf(v4) - 1.f);
  v5 = v5 > 0.f ? v5 : (__expf(v5) - 1.f);
  v6 = v6 > 0.f ? v6 : (__expf(v6) - 1.f);
  v7 = v7 > 0.f ? v7 : (__expf(v7) - 1.f);
  float s1 = ((v0 + v1) + (v2 + v3)) + ((v4 + v5) + (v6 + v7));
  float s2 = ((v0 * v0 + v1 * v1) + (v2 * v2 + v3 * v3)) +
             ((v4 * v4 + v5 * v5) + (v6 * v6 + v7 * v7));
#pragma unroll
  for (int o = 8; o > 0; o >>= 1) {
    s1 += __shfl_down(s1, o, 16);
    s2 += __shfl_down(s2, o, 16);
  }
  s1 = __shfl(s1, 0, 16);
  s2 = __shfl(s2, 0, 16);
  float mu = s1 * (1.f / HID);
  float var = s2 * (1.f / HID) - mu * mu;
  float inv = rsqrtf(var + LN_EPS);
  ushort4 q0, q1;
  q0.x = f2bf((v0 - mu) * inv * g[c0 + 0] + beta[c0 + 0]);
  q0.y = f2bf((v1 - mu) * inv * g[c0 + 1] + beta[c0 + 1]);
  q0.z = f2bf((v2 - mu) * inv * g[c0 + 2] + beta[c0 + 2]);
  q0.w = f2bf((v3 - mu) * inv * g[c0 + 3] + beta[c0 + 3]);
  q1.x = f2bf((v4 - mu) * inv * g[c0 + 4] + beta[c0 + 4]);
  q1.y = f2bf((v5 - mu) * inv * g[c0 + 5] + beta[c0 + 5]);
  q1.z = f2bf((v6 - mu) * inv * g[c0 + 6] + beta[c0 + 6]);
  q1.w = f2bf((v7 - mu) * inv * g[c0 + 7] + beta[c0 + 7]);
  *(ushort4*)(outb + (size_t)d * HID + c0) = q0;
  *(ushort4*)(outb + (size_t)d * HID + c0 + 4) = q1;
}

// ---------------------------------------------------------------------------
// Fused GAT agg + bias + ELU + LN, layer 2 (1 head). 16 threads/node.
// ---------------------------------------------------------------------------
__global__ __launch_bounds__(256) void k_agg2(
    const int* __restrict__ rowstart, const int* __restrict__ csr_src,
    const float* __restrict__ asrc, const float* __restrict__ adst,
    const unsigned short* __restrict__ hb, const float* __restrict__ bias,
    const float* __restrict__ g, const float* __restrict__ beta,
    float* __restrict__ out, int N) {
  int d = blockIdx.x * 16 + (threadIdx.x >> 4);
  if (d >= N) return;
  int lane = threadIdx.x & 15;
  int c0 = lane << 3;
  float ad = adst[d];
  int beg = rowstart[d], end = rowstart[d + 1];
  float a0 = 0.f, a1 = 0.f, a2 = 0.f, a3 = 0.f;
  float a4 = 0.f, a5 = 0.f, a6 = 0.f, a7 = 0.f, wsum = 0.f;
  int i = beg;
  for (; i + 4 <= end; i += 4) {
    int sA = csr_src[i], sB = csr_src[i + 1];
    int sC = csr_src[i + 2], sD = csr_src[i + 3];
    float vA = asrc[sA] + ad;
    float vB = asrc[sB] + ad;
    float vC = asrc[sC] + ad;
    float vD = asrc[sD] + ad;
    uint4 pA = *(const uint4*)(hb + (size_t)sA * HID + c0);
    uint4 pB = *(const uint4*)(hb + (size_t)sB * HID + c0);
    uint4 pC = *(const uint4*)(hb + (size_t)sC * HID + c0);
    uint4 pD = *(const uint4*)(hb + (size_t)sD * HID + c0);
    vA = vA < 0.f ? NEG * vA : vA;
    vB = vB < 0.f ? NEG * vB : vB;
    vC = vC < 0.f ? NEG * vC : vC;
    vD = vD < 0.f ? NEG * vD : vD;
    float wA = __expf(vA), wB = __expf(vB);
    float wC = __expf(vC), wD = __expf(vD);
    wsum += (wA + wB) + (wC + wD);
    a0 += wA * bflo(pA.x) + wB * bflo(pB.x) + wC * bflo(pC.x) + wD * bflo(pD.x);
    a1 += wA * bfhi(pA.x) + wB * bfhi(pB.x) + wC * bfhi(pC.x) + wD * bfhi(pD.x);
    a2 += wA * bflo(pA.y) + wB * bflo(pB.y) + wC * bflo(pC.y) + wD * bflo(pD.y);
    a3 += wA * bfhi(pA.y) + wB * bfhi(pB.y) + wC * bfhi(pC.y) + wD * bfhi(pD.y);
    a4 += wA * bflo(pA.z) + wB * bflo(pB.z) + wC * bflo(pC.z) + wD * bflo(pD.z);
    a5 += wA * bfhi(pA.z) + wB * bfhi(pB.z) + wC * bfhi(pC.z) + wD * bfhi(pD.z);
    a6 += wA * bflo(pA.w) + wB * bflo(pB.w) + wC * bflo(pC.w) + wD * bflo(pD.w);
    a7 += wA * bfhi(pA.w) + wB * bfhi(pB.w) + wC * bfhi(pC.w) + wD * bfhi(pD.w);
  }
  for (; i < end; ++i) {
    int sA = csr_src[i];
    float vA = asrc[sA] + ad;
    uint4 pA = *(const uint4*)(hb + (size_t)sA * HID + c0);
    vA = vA < 0.f ? NEG * vA : vA;
    float wA = __expf(vA);
    wsum += wA;
    a0 += wA * bflo(pA.x);
    a1 += wA * bfhi(pA.x);
    a2 += wA * bflo(pA.y);
    a3 += wA * bfhi(pA.y);
    a4 += wA * bflo(pA.z);
    a5 += wA * bfhi(pA.z);
    a6 += wA * bflo(pA.w);
    a7 += wA * bfhi(pA.w);
  }
  float rw = 1.f / wsum;
  float v0 = a0 * rw + bias[c0 + 0];
  float v1 = a1 * rw + bias[c0 + 1];
  float v2 = a2 * rw + bias[c0 + 2];
  float v3 = a3 * rw + bias[c0 + 3];
  float v4 = a4 * rw + bias[c0 + 4];
  float v5 = a5 * rw + bias[c0 + 5];
  float v6 = a6 * rw + bias[c0 + 6];
  float v7 = a7 * rw + bias[c0 + 7];
  v0 = v0 > 0.f ? v0 : (__expf(v0) - 1.f);
  v1 = v1 > 0.f ? v1 : (__expf(v1) - 1.f);
  v2 = v2 > 0.f ? v2 : (__expf(v2) - 1.f);
  v3 = v3 > 0.f ? v3 : (__expf(v3) - 1.f);
  v4 = v4 > 0.f ? v4 : (__expf(v4) - 1.f);
  v5 = v5 > 0.f ? v5 : (__expf(v5) - 1.f);
  v6 = v6 > 0.f ? v6 : (__expf(v6) - 1.f);
  v7 = v7 > 0.f ? v7 : (__expf(v7) - 1.f);
  float s1 = ((v0 + v1) + (v2 + v3)) + ((v4 + v5) + (v6 + v7));
  float s2 = ((v0 * v0 + v1 * v1) + (v2 * v2 + v3 * v3)) +
             ((v4 * v4 + v5 * v5) + (v6 * v6 + v7 * v7));
#pragma unroll
  for (int o = 8; o > 0; o >>= 1) {
    s1 += __shfl_down(s1, o, 16);
    s2 += __shfl_down(s2, o, 16);
  }
  s1 = __shfl(s1, 0, 16);
  s2 = __shfl(s2, 0, 16);
  float mu = s1 * (1.f / HID);
  float var = s2 * (1.f / HID) - mu * mu;
  float inv = rsqrtf(var + LN_EPS);
  float4 o0, o1;
  o0.x = (v0 - mu) * inv * g[c0 + 0] + beta[c0 + 0];
  o0.y = (v1 - mu) * inv * g[c0 + 1] + beta[c0 + 1];
  o0.z = (v2 - mu) * inv * g[c0 + 2] + beta[c0 + 2];
  o0.w = (v3 - mu) * inv * g[c0 + 3] + beta[c0 + 3];
  o1.x = (v4 - mu) * inv * g[c0 + 4] + beta[c0 + 4];
  o1.y = (v5 - mu) * inv * g[c0 + 5] + beta[c0 + 5];
  o1.z = (v6 - mu) * inv * g[c0 + 6] + beta[c0 + 6];
  o1.w = (v7 - mu) * inv * g[c0 + 7] + beta[c0 + 7];
  *(float4*)(out + (size_t)d * HID + c0) = o0;
  *(float4*)(out + (size_t)d * HID + c0 + 4) = o1;
}

// ---------------------------------------------------------------------------
// Pack W2 (f32 128x128) into MFMA B-fragment order, split into bf16 hi+lo.
// Fragment index: ((kb*8 + t)*64 + lane)*8 + i, with
//   k = kb*32 + (lane>>4)*8 + i,  col = t*16 + (lane&15).
// ---------------------------------------------------------------------------
__global__ __launch_bounds__(256) void k_w2pack(
    const float* __restrict__ W2, unsigned short* __restrict__ w2hi,
    unsigned short* __restrict__ w2lo) {
  int idx = blockIdx.x * 256 + threadIdx.x;  // 16384 total
  int i = idx & 7;
  int lane = (idx >> 3) & 63;
  int t = (idx >> 9) & 7;
  int kb = idx >> 12;
  int k = kb * 32 + (lane >> 4) * 8 + i;
  int c = t * 16 + (lane & 15);
  float w = W2[k * HID + c];
  unsigned short hi = f2bf(w);
  float res = w - bf2f(hi);
  w2hi[idx] = hi;
  w2lo[idx] = f2bf(res);
}

// ---------------------------------------------------------------------------
// h2 = x2 @ W2 via MFMA bf16 (W2 = Whi + Wlo split for f32-level accuracy).
// 4 waves/block, 16 nodes/wave. Epilogue via LDS transpose: bf16 h2 store +
// fused alpha2 logits.
// ---------------------------------------------------------------------------
__global__ __launch_bounds__(256) void k_gemm2m(
    const unsigned short* __restrict__ x2b,
    const unsigned short* __restrict__ w2hi,
    const unsigned short* __restrict__ w2lo,
    const float* __restrict__ a_src, const float* __restrict__ a_dst,
    unsigned short* __restrict__ h2b, float* __restrict__ asrc,
    float* __restrict__ adst, int N) {
  __shared__ float cs[4][16][132];
  int w = threadIdx.x >> 6;
  int l = threadIdx.x & 63;
  int n0 = blockIdx.x * 64 + w * 16;
  int m = l & 15;    // A row within tile
  int kg = l >> 4;   // k-group
  int na = n0 + m;
  if (na >= N) na = N - 1;  // clamp loads; garbage rows never stored
  const unsigned short* xrow = x2b + (size_t)na * HID + kg * 8;
  f32x4 acc[8] = {};
#pragma unroll
  for (int kb = 0; kb < 4; ++kb) {
    bf16x8 a = *(const bf16x8*)(xrow + kb * 32);
#pragma unroll
    for (int t = 0; t < 8; ++t) {
      bf16x8 bl = *(const bf16x8*)(w2lo + ((kb * 8 + t) * 64 + l) * 8);
      bf16x8 bh = *(const bf16x8*)(w2hi + ((kb * 8 + t) * 64 + l) * 8);
      acc[t] = __builtin_amdgcn_mfma_f32_16x16x32_bf16(a, bl, acc[t], 0, 0, 0);
      acc[t] = __builtin_amdgcn_mfma_f32_16x16x32_bf16(a, bh, acc[t], 0, 0, 0);
    }
  }
  // C/D layout (measured): col = lane&15, row = (lane>>4)*4 + reg.
#pragma unroll
  for (int t = 0; t < 8; ++t)
#pragma unroll
    for (int j = 0; j < 4; ++j) cs[w][kg * 4 + j][t * 16 + m] = acc[t][j];
  __syncthreads();
  // read back row-contiguous: lane -> node row (l&15), col quarter (l>>4)
  int r2 = l & 15;
  int q = l >> 4;
  int n = n0 + r2;
  if (n < N) {
    const float* rowp = &cs[w][r2][0];
    float pa = 0.f, pd = 0.f;
#pragma unroll
    for (int j = 0; j < 8; ++j) {
      int cc = q * 32 + j * 4;
      float4 v = *(const float4*)(rowp + cc);
      float4 as = *(const float4*)(a_src + cc);
      float4 av = *(const float4*)(a_dst + cc);
      pa += v.x * as.x + v.y * as.y + v.z * as.z + v.w * as.w;
      pd += v.x * av.x + v.y * av.y + v.z * av.z + v.w * av.w;
      ushort4 ob;
      ob.x = f2bf(v.x);
      ob.y = f2bf(v.y);
      ob.z = f2bf(v.z);
      ob.w = f2bf(v.w);
      *(ushort4*)(h2b + (size_t)n * HID + cc) = ob;
    }
    pa += __shfl_xor(pa, 16, 64);
    pa += __shfl_xor(pa, 32, 64);
    pd += __shfl_xor(pd, 16, 64);
    pd += __shfl_xor(pd, 32, 64);
    if (q == 0) {
      asrc[n] = pa;
      adst[n] = pd;
    }
  }
}

extern "C" void kernel_launch(void* const* d_in, const int* in_sizes, int n_in,
                              void* d_out, int out_size, void* d_ws, size_t ws_size,
                              hipStream_t stream) {
  const float* x      = (const float*)d_in[0];
  const int*   ei     = (const int*)d_in[1];
  const float* W1     = (const float*)d_in[2];
  const float* a_src1 = (const float*)d_in[3];
  const float* a_dst1 = (const float*)d_in[4];
  const float* b1     = (const float*)d_in[5];
  const float* g1     = (const float*)d_in[6];
  const float* beta1  = (const float*)d_in[7];
  const float* W2     = (const float*)d_in[8];
  const float* a_src2 = (const float*)d_in[9];
  const float* a_dst2 = (const float*)d_in[10];
  const float* b2     = (const float*)d_in[11];
  const float* g2     = (const float*)d_in[12];
  const float* beta2  = (const float*)d_in[13];
  float* out = (float*)d_out;

  const int N = in_sizes[0] / IN_CH;
  const int E = in_sizes[1] / 2;
  const int Etot = E + N;
  const int nblk = (N + 255) / 256;

  // workspace layout (all chunks 16B-aligned)
  unsigned short* hb  = (unsigned short*)d_ws;          // h1 bf16 -> h2 bf16
  unsigned short* x2b = hb + (size_t)N * HID;           // x2 bf16
  float* asrc1 = (float*)(x2b + (size_t)N * HID);
  float* adst1 = asrc1 + (size_t)N * HEADS;
  float* asrc2 = adst1 + (size_t)N * HEADS;
  float* adst2 = asrc2 + N;
  int* deg      = (int*)(adst2 + N);
  int* part     = deg + N;
  int* rowstart = part + N;           // [N+1] padded to N+4
  int* aux      = rowstart + N + 4;   // [<=1024]
  int* csr_src  = aux + 1024;         // [Etot]
  int* rank     = csr_src + Etot;     // [Etot]
  unsigned short* w2hi = (unsigned short*)(rank + Etot);  // [16384]
  unsigned short* w2lo = w2hi + 16384;                    // [16384]

  // ---- W2 fragment pack (independent of everything else) ----
  k_w2pack<<<64, 256, 0, stream>>>(W2, w2hi, w2lo);

  // ---- CSR build (shared by both layers) ----
  hipMemsetAsync(deg, 0, (size_t)N * sizeof(int), stream);
  k_deg<<<(Etot + 255) / 256, 256, 0, stream>>>(ei, E, Etot, deg, rank);
  k_scan1<<<nblk, 256, 0, stream>>>(deg, part, aux, N);
  k_scan2<<<1, 512, 0, stream>>>(aux, nblk);
  k_scan3<<<nblk, 256, 0, stream>>>(part, aux, rowstart, N, Etot);
  k_scatter<<<(Etot + 255) / 256, 256, 0, stream>>>(ei, rowstart, rank, E, Etot,
                                                    csr_src);

  // ---- Layer 1 ----
  k_gemm1<<<N, 128, 0, stream>>>(x, W1, a_src1, a_dst1, hb, asrc1, adst1, N);
  k_agg1<<<(N + 15) / 16, 256, 0, stream>>>(rowstart, csr_src, asrc1, adst1, hb,
                                            b1, g1, beta1, x2b, N);

  // ---- Layer 2 ----  (h2 bf16 reuses hb; h1 dead after agg1)
  k_gemm2m<<<(N + 63) / 64, 256, 0, stream>>>(x2b, w2hi, w2lo, a_src2, a_dst2,
                                              hb, asrc2, adst2, N);
  k_agg2<<<(N + 15) / 16, 256, 0, stream>>>(rowstart, csr_src, asrc2, adst2, hb,
                                            b2, g2, beta2, out, N);
}